// Round 5
// baseline (374.031 us; speedup 1.0000x reference)
//
#include <hip/hip_runtime.h>
#include <stdint.h>

#define T_ 512
#define K_ 256
#define NB 16
#define WROW 264  // padded W row stride in ushorts (528 B): conflict-free writes
#define L2E 1.4426950408889634f
#define LN2 0.6931471805599453f

typedef __attribute__((ext_vector_type(8))) short short8;
typedef __attribute__((ext_vector_type(4))) float f32x4;

__device__ __forceinline__ float fexp2(float x) {
#if __has_builtin(__builtin_amdgcn_exp2f)
  return __builtin_amdgcn_exp2f(x);
#else
  return exp2f(x);
#endif
}
__device__ __forceinline__ float flog2(float x) {
#if __has_builtin(__builtin_amdgcn_logf)
  return __builtin_amdgcn_logf(x);
#else
  return log2f(x);
#endif
}
__device__ __forceinline__ unsigned int umax_(unsigned int a, unsigned int b) {
  return a > b ? a : b;
}
__device__ __forceinline__ unsigned short f2bf(float f) {
  union { float f; uint32_t u; } v; v.f = f;
  uint32_t r = v.u + 0x7fffu + ((v.u >> 16) & 1u);
  return (unsigned short)(r >> 16);
}
// RNE pack of two f32 -> one dword of 2 bf16 (lo = a, hi = b)
__device__ __forceinline__ uint32_t cvt_pk_bf16(float a, float b) {
  uint32_t d;
  asm("v_cvt_pk_bf16_f32 %0, %1, %2" : "=v"(d) : "v"(a), "v"(b));
  return d;
}

// lgkm-only barrier: global loads stay in flight across it
#define BAR() do { \
  asm volatile("s_waitcnt lgkmcnt(0)" ::: "memory"); \
  __builtin_amdgcn_s_barrier(); \
  asm volatile("" ::: "memory"); \
} while (0)

// ---------- aux kernels (proven) ----------

__global__ void prep_E(const float* __restrict__ trans, unsigned short* __restrict__ Efrag) {
  int idx = blockIdx.x * 256 + threadIdx.x;  // 0..65535
  int e = idx & 7;
  int ln = (idx >> 3) & 63;
  int kb = (idx >> 9) & 7;
  int mt = idx >> 12;
  int j = mt * 16 + (ln & 15);
  int k = kb * 32 + ((ln >> 4) << 3) + e;
  Efrag[idx] = f2bf(__expf(trans[k * K_ + j]));
}

__global__ void aux_mask(const float* __restrict__ yp, unsigned char* __restrict__ masks) {
  int item = blockIdx.x * 4 + (threadIdx.x >> 6);  // b*512 + t
  int lane = threadIdx.x & 63;
  const float4 v = *(const float4*)(yp + (size_t)item * K_ + lane * 4);
  float mn = fminf(fminf(v.x, v.y), fminf(v.z, v.w));
  unsigned long long bl = __ballot(mn > -1000000.0f);
  if (lane == 0) {
    int b = item >> 9, t = item & 511;
    masks[t * 128 + b] = (bl == ~0ull) ? 1 : 0;
  }
}

__global__ void aux_score(const float* __restrict__ yp, const float* __restrict__ trans,
                          const int* __restrict__ ytrue, const unsigned char* __restrict__ masks,
                          float* __restrict__ score) {
  int b = blockIdx.x;
  int lane = threadIdx.x;  // 0..63
  float s = 0.f;
  #pragma unroll
  for (int k = 0; k < 8; ++k) {
    int t = lane + 64 * k;
    int y = ytrue[b * T_ + t];
    int m = masks[t * 128 + b];
    float x = yp[((size_t)b * T_ + t) * K_ + y];
    if (m) s += x;
    if (t >= 1) {
      int ym = ytrue[b * T_ + t - 1];
      int mm = masks[(t - 1) * 128 + b];
      if (m && mm) s += trans[ym * K_ + y];
    }
  }
  #pragma unroll
  for (int off = 32; off; off >>= 1) s += __shfl_xor(s, off, 64);
  if (lane == 0) score[b] = s;
}

// ---------- scan ----------

template<int TM4, bool RESC, bool MWR, bool MASKED>
__device__ __forceinline__ void crf_step(
    int t, int c, int g, int wv, const int* tb,
    const short8 (&Ef)[4][8],
    float (&a)[16], float (&exf)[16], int& acc, int& mkc,
    const float* xb, float4 (&XN)[4], float4 (&XI)[4],
    unsigned short (*Wl)[NB * WROW], const unsigned char* mkl, unsigned int* Mpart) {
  BAR();
  // rescale (off the MFMA critical path; once per 4 steps)
  if (RESC) {
    unsigned int Mx = Mpart[c];
    Mx = umax_(Mx, Mpart[NB + c]);
    Mx = umax_(Mx, Mpart[2 * NB + c]);
    Mx = umax_(Mx, Mpart[3 * NB + c]);
    unsigned int e_ = Mx >> 23;
    float sf = __builtin_bit_cast(float, (254u - e_) << 23);
    if (!MASKED || mkc) acc += 127 - (int)e_;
    #pragma unroll
    for (int j = 0; j < 16; ++j) exf[j] *= sf;
  }
  // GEMM: S[tag][batch] = sum_i w[batch][i] * E[i][tag]
  // 8 independent accumulation chains (depth 4) to hide MFMA dep latency.
  f32x4 acA[4], acB[4];
  #pragma unroll
  for (int m = 0; m < 4; ++m) { acA[m] = (f32x4){0.f,0.f,0.f,0.f}; acB[m] = (f32x4){0.f,0.f,0.f,0.f}; }
  {
    const unsigned short* rrow = &Wl[TM4 & 1][c * WROW];
    __builtin_amdgcn_s_setprio(1);
    #pragma unroll
    for (int kb = 0; kb < 4; ++kb) {
      short8 bf = __builtin_bit_cast(short8, *(const uint4*)(&rrow[kb * 32 + g * 8]));
      acA[0] = __builtin_amdgcn_mfma_f32_16x16x32_bf16(Ef[0][kb], bf, acA[0], 0, 0, 0);
      acA[1] = __builtin_amdgcn_mfma_f32_16x16x32_bf16(Ef[1][kb], bf, acA[1], 0, 0, 0);
      acA[2] = __builtin_amdgcn_mfma_f32_16x16x32_bf16(Ef[2][kb], bf, acA[2], 0, 0, 0);
      acA[3] = __builtin_amdgcn_mfma_f32_16x16x32_bf16(Ef[3][kb], bf, acA[3], 0, 0, 0);
    }
    #pragma unroll
    for (int kb = 4; kb < 8; ++kb) {
      short8 bf = __builtin_bit_cast(short8, *(const uint4*)(&rrow[kb * 32 + g * 8]));
      acB[0] = __builtin_amdgcn_mfma_f32_16x16x32_bf16(Ef[0][kb], bf, acB[0], 0, 0, 0);
      acB[1] = __builtin_amdgcn_mfma_f32_16x16x32_bf16(Ef[1][kb], bf, acB[1], 0, 0, 0);
      acB[2] = __builtin_amdgcn_mfma_f32_16x16x32_bf16(Ef[2][kb], bf, acB[2], 0, 0, 0);
      acB[3] = __builtin_amdgcn_mfma_f32_16x16x32_bf16(Ef[3][kb], bf, acB[3], 0, 0, 0);
    }
    __builtin_amdgcn_s_setprio(0);
  }
  // alpha update
  if (MASKED) {
    #pragma unroll
    for (int m = 0; m < 4; ++m)
      #pragma unroll
      for (int i = 0; i < 4; ++i) {
        float an = (acA[m][i] + acB[m][i]) * exf[4 * m + i];
        a[4 * m + i] = mkc ? an : a[4 * m + i];
      }
  } else {
    #pragma unroll
    for (int m = 0; m < 4; ++m)
      #pragma unroll
      for (int i = 0; i < 4; ++i)
        a[4 * m + i] = (acA[m][i] + acB[m][i]) * exf[4 * m + i];
  }
  // pack alpha -> bf16 (RNE), write W[(t+1)&1]
  {
    unsigned short* wrow = &Wl[(TM4 + 1) & 1][c * WROW];
    #pragma unroll
    for (int m = 0; m < 4; ++m) {
      uint2 pp;
      pp.x = cvt_pk_bf16(a[4 * m + 0], a[4 * m + 1]);
      pp.y = cvt_pk_bf16(a[4 * m + 2], a[4 * m + 3]);
      *(uint2*)(&wrow[tb[m]]) = pp;
    }
  }
  // partial max of alpha for the next rescale
  if (MWR) {
    unsigned int pm = __builtin_bit_cast(uint32_t, a[0]);
    #pragma unroll
    for (int j = 1; j < 16; ++j) pm = umax_(pm, __builtin_bit_cast(uint32_t, a[j]));
    pm = umax_(pm, (unsigned int)__shfl_xor((int)pm, 16, 64));
    pm = umax_(pm, (unsigned int)__shfl_xor((int)pm, 32, 64));
    if (g == 0) Mpart[wv * NB + c] = pm;
  }
  // exf for step t+1 (in MFMA/pack shadow; slot XN loaded >=3 steps ago)
  #pragma unroll
  for (int m = 0; m < 4; ++m) {
    exf[4 * m + 0] = fexp2(XN[m].x * L2E);
    exf[4 * m + 1] = fexp2(XN[m].y * L2E);
    exf[4 * m + 2] = fexp2(XN[m].z * L2E);
    exf[4 * m + 3] = fexp2(XN[m].w * L2E);
  }
  if (MASKED) mkc = mkl[(t + 1 < T_ ? t + 1 : 0) * NB + c];
  // issue x(t+4) into the just-freed slot
  {
    int tt = t + 4;
    tt = tt > (T_ - 1) ? (T_ - 1) : tt;
    #pragma unroll
    for (int m = 0; m < 4; ++m)
      XI[m] = *(const float4*)(xb + (size_t)tt * K_ + tb[m]);
  }
}

template<bool MASKED>
__device__ __forceinline__ void scan_run(
    int tid, int c, int g, int wv, const int* tb, int b0,
    const short8 (&Ef)[4][8], const float* xb,
    float4 (&xinit)[4], float4 (&X0q)[4], float4 (&X1q)[4],
    float4 (&X2q)[4], float4 (&X3q)[4],
    unsigned short (*Wl)[NB * WROW], const unsigned char* mkl,
    unsigned int* Mpart, float* Spart,
    const float* __restrict__ score, float* __restrict__ out) {
  float a[16], exf[16];
  int acc = 0;
  int mkc = 0;
  // alpha(0), linear domain
  {
    int mk0 = MASKED ? mkl[c] : 1;
    #pragma unroll
    for (int m = 0; m < 4; ++m) {
      float e0 = fexp2(xinit[m].x * L2E);
      float e1 = fexp2(xinit[m].y * L2E);
      float e2 = fexp2(xinit[m].z * L2E);
      float e3 = fexp2(xinit[m].w * L2E);
      a[4 * m + 0] = (MASKED && !mk0) ? 1.0f : e0;
      a[4 * m + 1] = (MASKED && !mk0) ? 1.0f : e1;
      a[4 * m + 2] = (MASKED && !mk0) ? 1.0f : e2;
      a[4 * m + 3] = (MASKED && !mk0) ? 1.0f : e3;
    }
  }
  // W[1] <- bf16(alpha(0))  (step t=1 reads parity 1)
  {
    unsigned short* wrow = &Wl[1][c * WROW];
    #pragma unroll
    for (int m = 0; m < 4; ++m) {
      uint2 pp;
      pp.x = cvt_pk_bf16(a[4 * m + 0], a[4 * m + 1]);
      pp.y = cvt_pk_bf16(a[4 * m + 2], a[4 * m + 3]);
      *(uint2*)(&wrow[tb[m]]) = pp;
    }
  }
  // exf(1) from X1q; mask(1)
  #pragma unroll
  for (int m = 0; m < 4; ++m) {
    exf[4 * m + 0] = fexp2(X1q[m].x * L2E);
    exf[4 * m + 1] = fexp2(X1q[m].y * L2E);
    exf[4 * m + 2] = fexp2(X1q[m].z * L2E);
    exf[4 * m + 3] = fexp2(X1q[m].w * L2E);
  }
  if (MASKED) mkc = mkl[NB + c];

  // prologue t = 1..3
  crf_step<1, false, false, MASKED>(1, c, g, wv, tb, Ef, a, exf, acc, mkc, xb, X2q, X1q, Wl, mkl, Mpart);
  crf_step<2, false, false, MASKED>(2, c, g, wv, tb, Ef, a, exf, acc, mkc, xb, X3q, X2q, Wl, mkl, Mpart);
  crf_step<3, false, true , MASKED>(3, c, g, wv, tb, Ef, a, exf, acc, mkc, xb, X0q, X3q, Wl, mkl, Mpart);

  #pragma unroll 1
  for (int t0 = 4; t0 < T_; t0 += 4) {
    crf_step<0, true , false, MASKED>(t0,     c, g, wv, tb, Ef, a, exf, acc, mkc, xb, X1q, X0q, Wl, mkl, Mpart);
    crf_step<1, false, false, MASKED>(t0 + 1, c, g, wv, tb, Ef, a, exf, acc, mkc, xb, X2q, X1q, Wl, mkl, Mpart);
    crf_step<2, false, false, MASKED>(t0 + 2, c, g, wv, tb, Ef, a, exf, acc, mkc, xb, X3q, X2q, Wl, mkl, Mpart);
    crf_step<3, false, true , MASKED>(t0 + 3, c, g, wv, tb, Ef, a, exf, acc, mkc, xb, X0q, X3q, Wl, mkl, Mpart);
  }

  // final: out = ln2*(log2(sum alpha) - acc) - score
  __syncthreads();
  {
    float ssum = 0.f;
    #pragma unroll
    for (int j = 0; j < 16; ++j) ssum += a[j];
    ssum += __shfl_xor(ssum, 16, 64);
    ssum += __shfl_xor(ssum, 32, 64);
    if (g == 0) Spart[wv * NB + c] = ssum;
  }
  __syncthreads();
  if (tid < NB) {
    float S = Spart[tid] + Spart[NB + tid] + Spart[2 * NB + tid] + Spart[3 * NB + tid];
    out[b0 + tid] = LN2 * (flog2(S) - (float)acc) - score[b0 + tid];
  }
}

__global__ __launch_bounds__(256, 1) void crf_scan(
    const float* __restrict__ yp, const unsigned short* __restrict__ Efrag,
    const unsigned char* __restrict__ masks, const float* __restrict__ score,
    float* __restrict__ out) {
  const int b0 = blockIdx.x * NB;
  const int tid = threadIdx.x;
  const int wv = tid >> 6, lane = tid & 63;
  const int c = lane & 15;       // batch column
  const int g = lane >> 4;       // k-group / row-group

  __shared__ unsigned short Wl[2][NB * WROW];  // ~16.9 KB
  __shared__ unsigned char mkl[T_ * NB];       // 8 KB
  __shared__ unsigned int Mpart[4 * NB];
  __shared__ float Spart[4 * NB];
  __shared__ int sflag[4];

  // E fragments -> registers: wave wv owns M-tiles wv*4..wv*4+3
  short8 Ef[4][8];
  {
    const uint4* ep = (const uint4*)Efrag;
    #pragma unroll
    for (int m = 0; m < 4; ++m)
      #pragma unroll
      for (int kb = 0; kb < 8; ++kb)
        Ef[m][kb] = __builtin_bit_cast(short8, ep[((wv * 4 + m) * 8 + kb) * 64 + lane]);
  }

  // mask table -> LDS (mkl[t*16 + c]); also gather all-ones check
  uint4 md0, md1;
  {
    uint4* dst = (uint4*)mkl;
    md0 = *(const uint4*)(masks + (tid)*128 + b0);
    md1 = *(const uint4*)(masks + (tid + 256) * 128 + b0);
    dst[tid] = md0;
    dst[tid + 256] = md1;
  }

  const float* xb = yp + (size_t)(b0 + c) * T_ * K_;
  int tb[4];
  #pragma unroll
  for (int m = 0; m < 4; ++m) tb[m] = wv * 64 + m * 16 + g * 4;

  float4 xinit[4], X0q[4], X1q[4], X2q[4], X3q[4];
  #pragma unroll
  for (int m = 0; m < 4; ++m) xinit[m] = *(const float4*)(xb + tb[m]);
  #pragma unroll
  for (int m = 0; m < 4; ++m) X1q[m] = *(const float4*)(xb + 1 * K_ + tb[m]);
  #pragma unroll
  for (int m = 0; m < 4; ++m) X2q[m] = *(const float4*)(xb + 2 * K_ + tb[m]);
  #pragma unroll
  for (int m = 0; m < 4; ++m) X3q[m] = *(const float4*)(xb + 3 * K_ + tb[m]);
  #pragma unroll
  for (int m = 0; m < 4; ++m) X0q[m] = *(const float4*)(xb + 4 * K_ + tb[m]);

  // all-masks-one check (block-uniform)
  {
    uint32_t w = md0.x & md0.y & md0.z & md0.w & md1.x & md1.y & md1.z & md1.w;
    unsigned long long bl = __ballot(w == 0x01010101u);
    if (lane == 0) sflag[wv] = (bl == ~0ull) ? 1 : 0;
  }
  __syncthreads();
  bool allm = sflag[0] && sflag[1] && sflag[2] && sflag[3];

  if (allm) {
    scan_run<false>(tid, c, g, wv, tb, b0, Ef, xb, xinit, X0q, X1q, X2q, X3q,
                    Wl, mkl, Mpart, Spart, score, out);
  } else {
    scan_run<true>(tid, c, g, wv, tb, b0, Ef, xb, xinit, X0q, X1q, X2q, X3q,
                   Wl, mkl, Mpart, Spart, score, out);
  }
}

extern "C" void kernel_launch(void* const* d_in, const int* in_sizes, int n_in,
                              void* d_out, int out_size, void* d_ws, size_t ws_size,
                              hipStream_t stream) {
  const float* yp = (const float*)d_in[0];
  const float* trans = (const float*)d_in[1];
  const int* ytrue = (const int*)d_in[2];
  float* out = (float*)d_out;

  unsigned short* Efrag = (unsigned short*)d_ws;                 // 128 KB
  unsigned char* masks = (unsigned char*)d_ws + 131072;          // 64 KB
  float* score = (float*)((char*)d_ws + 131072 + 65536);         // 512 B

  prep_E<<<dim3(256), dim3(256), 0, stream>>>(trans, Efrag);
  aux_mask<<<dim3(16384), dim3(256), 0, stream>>>(yp, masks);
  aux_score<<<dim3(128), dim3(64), 0, stream>>>(yp, trans, ytrue, masks, score);
  crf_scan<<<dim3(8), dim3(256), 0, stream>>>(yp, Efrag, masks, score, out);
}

// Round 6
// 302.046 us; speedup vs baseline: 1.2383x; 1.2383x over previous
//
#include <hip/hip_runtime.h>
#include <stdint.h>

#define T_ 512
#define K_ 256
#define NB 16
#define WROW 264  // padded W row stride in ushorts (528 B)
#define L2E 1.4426950408889634f
#define LN2 0.6931471805599453f

typedef __attribute__((ext_vector_type(8))) short short8;
typedef __attribute__((ext_vector_type(4))) float f32x4;

__device__ __forceinline__ float fexp2(float x) {
#if __has_builtin(__builtin_amdgcn_exp2f)
  return __builtin_amdgcn_exp2f(x);
#else
  return exp2f(x);
#endif
}
__device__ __forceinline__ float flog2(float x) {
#if __has_builtin(__builtin_amdgcn_logf)
  return __builtin_amdgcn_logf(x);
#else
  return log2f(x);
#endif
}
__device__ __forceinline__ unsigned int umax_(unsigned int a, unsigned int b) {
  return a > b ? a : b;
}
__device__ __forceinline__ unsigned short f2bf(float f) {
  union { float f; uint32_t u; } v; v.f = f;
  uint32_t r = v.u + 0x7fffu + ((v.u >> 16) & 1u);
  return (unsigned short)(r >> 16);
}
// RNE pack of two f32 -> one dword of 2 bf16 (lo = a, hi = b)
__device__ __forceinline__ uint32_t cvt_pk_bf16(float a, float b) {
  uint32_t d;
  asm("v_cvt_pk_bf16_f32 %0, %1, %2" : "=v"(d) : "v"(a), "v"(b));
  return d;
}

// lgkm-only barrier: global loads stay in flight across it
#define BAR() do { \
  asm volatile("s_waitcnt lgkmcnt(0)" ::: "memory"); \
  __builtin_amdgcn_s_barrier(); \
  asm volatile("" ::: "memory"); \
} while (0)

// ---------- aux kernels (proven) ----------

__global__ void prep_E(const float* __restrict__ trans, unsigned short* __restrict__ Efrag) {
  int idx = blockIdx.x * 256 + threadIdx.x;  // 0..65535
  int e = idx & 7;
  int ln = (idx >> 3) & 63;
  int kb = (idx >> 9) & 7;
  int mt = idx >> 12;
  int j = mt * 16 + (ln & 15);
  int k = kb * 32 + ((ln >> 4) << 3) + e;
  Efrag[idx] = f2bf(__expf(trans[k * K_ + j]));
}

__global__ void aux_mask(const float* __restrict__ yp, unsigned char* __restrict__ masks) {
  int item = blockIdx.x * 4 + (threadIdx.x >> 6);  // b*512 + t
  int lane = threadIdx.x & 63;
  const float4 v = *(const float4*)(yp + (size_t)item * K_ + lane * 4);
  float mn = fminf(fminf(v.x, v.y), fminf(v.z, v.w));
  unsigned long long bl = __ballot(mn > -1000000.0f);
  if (lane == 0) {
    int b = item >> 9, t = item & 511;
    masks[t * 128 + b] = (bl == ~0ull) ? 1 : 0;
  }
}

__global__ void aux_score(const float* __restrict__ yp, const float* __restrict__ trans,
                          const int* __restrict__ ytrue, const unsigned char* __restrict__ masks,
                          float* __restrict__ score) {
  int b = blockIdx.x;
  int lane = threadIdx.x;  // 0..63
  float s = 0.f;
  #pragma unroll
  for (int k = 0; k < 8; ++k) {
    int t = lane + 64 * k;
    int y = ytrue[b * T_ + t];
    int m = masks[t * 128 + b];
    float x = yp[((size_t)b * T_ + t) * K_ + y];
    if (m) s += x;
    if (t >= 1) {
      int ym = ytrue[b * T_ + t - 1];
      int mm = masks[(t - 1) * 128 + b];
      if (m && mm) s += trans[ym * K_ + y];
    }
  }
  #pragma unroll
  for (int off = 32; off; off >>= 1) s += __shfl_xor(s, off, 64);
  if (lane == 0) score[b] = s;
}

// ---------- scan: 8 waves (2/SIMD), wave wv owns M-tiles {2wv, 2wv+1} ----------

template<int TM4, bool RESC, bool MWR, bool MASKED>
__device__ __forceinline__ void crf_step(
    int t, int c, int g, int wv, const int* tb,
    const short8 (&Ef)[2][8],
    float (&a)[8], float (&exf)[8], int& acc, int& mkc,
    const float* xb, float4 (&XN)[2], float4 (&XI)[2],
    unsigned short (*Wl)[NB * WROW], const unsigned char* mkl, unsigned int* Mpart) {
  BAR();
  // rescale (once per 4 steps, off the MFMA critical path)
  if (RESC) {
    unsigned int Mx = Mpart[c];
    #pragma unroll
    for (int w = 1; w < 8; ++w) Mx = umax_(Mx, Mpart[w * NB + c]);
    unsigned int e_ = Mx >> 23;
    float sf = __builtin_bit_cast(float, (254u - e_) << 23);
    if (!MASKED || mkc) acc += 127 - (int)e_;
    #pragma unroll
    for (int j = 0; j < 8; ++j) exf[j] *= sf;
  }
  // GEMM: S[tag][batch] = sum_i w[batch][i] * E[i][tag]
  f32x4 ac0 = {0.f, 0.f, 0.f, 0.f}, ac1 = {0.f, 0.f, 0.f, 0.f};
  {
    const unsigned short* rrow = &Wl[TM4 & 1][c * WROW];
    #pragma unroll
    for (int kb = 0; kb < 8; ++kb) {
      short8 bf = __builtin_bit_cast(short8, *(const uint4*)(&rrow[kb * 32 + g * 8]));
      ac0 = __builtin_amdgcn_mfma_f32_16x16x32_bf16(Ef[0][kb], bf, ac0, 0, 0, 0);
      ac1 = __builtin_amdgcn_mfma_f32_16x16x32_bf16(Ef[1][kb], bf, ac1, 0, 0, 0);
    }
  }
  // alpha update
  if (MASKED) {
    #pragma unroll
    for (int i = 0; i < 4; ++i) { float an = ac0[i] * exf[i];     a[i]     = mkc ? an : a[i]; }
    #pragma unroll
    for (int i = 0; i < 4; ++i) { float an = ac1[i] * exf[4 + i]; a[4 + i] = mkc ? an : a[4 + i]; }
  } else {
    #pragma unroll
    for (int i = 0; i < 4; ++i) a[i]     = ac0[i] * exf[i];
    #pragma unroll
    for (int i = 0; i < 4; ++i) a[4 + i] = ac1[i] * exf[4 + i];
  }
  // pack alpha -> bf16 (RNE), write W[(t+1)&1]
  {
    unsigned short* wrow = &Wl[(TM4 + 1) & 1][c * WROW];
    #pragma unroll
    for (int m = 0; m < 2; ++m) {
      uint2 pp;
      pp.x = cvt_pk_bf16(a[4 * m + 0], a[4 * m + 1]);
      pp.y = cvt_pk_bf16(a[4 * m + 2], a[4 * m + 3]);
      *(uint2*)(&wrow[tb[m]]) = pp;
    }
  }
  // partial max of alpha for the next rescale
  if (MWR) {
    unsigned int pm = __builtin_bit_cast(uint32_t, a[0]);
    #pragma unroll
    for (int j = 1; j < 8; ++j) pm = umax_(pm, __builtin_bit_cast(uint32_t, a[j]));
    pm = umax_(pm, (unsigned int)__shfl_xor((int)pm, 16, 64));
    pm = umax_(pm, (unsigned int)__shfl_xor((int)pm, 32, 64));
    if (g == 0) Mpart[wv * NB + c] = pm;
  }
  // exf for step t+1 (slot XN loaded >= 3 steps ago)
  #pragma unroll
  for (int m = 0; m < 2; ++m) {
    exf[4 * m + 0] = fexp2(XN[m].x * L2E);
    exf[4 * m + 1] = fexp2(XN[m].y * L2E);
    exf[4 * m + 2] = fexp2(XN[m].z * L2E);
    exf[4 * m + 3] = fexp2(XN[m].w * L2E);
  }
  if (MASKED) mkc = mkl[(t + 1 < T_ ? t + 1 : 0) * NB + c];
  // issue x(t+4) into the just-freed slot
  {
    int tt = t + 4;
    tt = tt > (T_ - 1) ? (T_ - 1) : tt;
    #pragma unroll
    for (int m = 0; m < 2; ++m)
      XI[m] = *(const float4*)(xb + (size_t)tt * K_ + tb[m]);
  }
}

template<bool MASKED>
__device__ __forceinline__ void scan_run(
    int tid, int c, int g, int wv, const int* tb, int b0,
    const short8 (&Ef)[2][8], const float* xb,
    float4 (&xinit)[2], float4 (&X0q)[2], float4 (&X1q)[2],
    float4 (&X2q)[2], float4 (&X3q)[2],
    unsigned short (*Wl)[NB * WROW], const unsigned char* mkl,
    unsigned int* Mpart, float* Spart,
    const float* __restrict__ score, float* __restrict__ out) {
  float a[8], exf[8];
  int acc = 0;
  int mkc = 0;
  // alpha(0), linear domain
  {
    int mk0 = MASKED ? mkl[c] : 1;
    #pragma unroll
    for (int m = 0; m < 2; ++m) {
      float e0 = fexp2(xinit[m].x * L2E);
      float e1 = fexp2(xinit[m].y * L2E);
      float e2 = fexp2(xinit[m].z * L2E);
      float e3 = fexp2(xinit[m].w * L2E);
      a[4 * m + 0] = (MASKED && !mk0) ? 1.0f : e0;
      a[4 * m + 1] = (MASKED && !mk0) ? 1.0f : e1;
      a[4 * m + 2] = (MASKED && !mk0) ? 1.0f : e2;
      a[4 * m + 3] = (MASKED && !mk0) ? 1.0f : e3;
    }
  }
  // W[1] <- bf16(alpha(0))  (step t=1 reads parity 1)
  {
    unsigned short* wrow = &Wl[1][c * WROW];
    #pragma unroll
    for (int m = 0; m < 2; ++m) {
      uint2 pp;
      pp.x = cvt_pk_bf16(a[4 * m + 0], a[4 * m + 1]);
      pp.y = cvt_pk_bf16(a[4 * m + 2], a[4 * m + 3]);
      *(uint2*)(&wrow[tb[m]]) = pp;
    }
  }
  // exf(1) from X1q; mask(1)
  #pragma unroll
  for (int m = 0; m < 2; ++m) {
    exf[4 * m + 0] = fexp2(X1q[m].x * L2E);
    exf[4 * m + 1] = fexp2(X1q[m].y * L2E);
    exf[4 * m + 2] = fexp2(X1q[m].z * L2E);
    exf[4 * m + 3] = fexp2(X1q[m].w * L2E);
  }
  if (MASKED) mkc = mkl[NB + c];

  // prologue t = 1..3
  crf_step<1, false, false, MASKED>(1, c, g, wv, tb, Ef, a, exf, acc, mkc, xb, X2q, X1q, Wl, mkl, Mpart);
  crf_step<2, false, false, MASKED>(2, c, g, wv, tb, Ef, a, exf, acc, mkc, xb, X3q, X2q, Wl, mkl, Mpart);
  crf_step<3, false, true , MASKED>(3, c, g, wv, tb, Ef, a, exf, acc, mkc, xb, X0q, X3q, Wl, mkl, Mpart);

  #pragma unroll 1
  for (int t0 = 4; t0 < T_; t0 += 4) {
    crf_step<0, true , false, MASKED>(t0,     c, g, wv, tb, Ef, a, exf, acc, mkc, xb, X1q, X0q, Wl, mkl, Mpart);
    crf_step<1, false, false, MASKED>(t0 + 1, c, g, wv, tb, Ef, a, exf, acc, mkc, xb, X2q, X1q, Wl, mkl, Mpart);
    crf_step<2, false, false, MASKED>(t0 + 2, c, g, wv, tb, Ef, a, exf, acc, mkc, xb, X3q, X2q, Wl, mkl, Mpart);
    crf_step<3, false, true , MASKED>(t0 + 3, c, g, wv, tb, Ef, a, exf, acc, mkc, xb, X0q, X3q, Wl, mkl, Mpart);
  }

  // final: out = ln2*(log2(sum alpha) - acc) - score
  __syncthreads();
  {
    float ssum = 0.f;
    #pragma unroll
    for (int j = 0; j < 8; ++j) ssum += a[j];
    ssum += __shfl_xor(ssum, 16, 64);
    ssum += __shfl_xor(ssum, 32, 64);
    if (g == 0) Spart[wv * NB + c] = ssum;
  }
  __syncthreads();
  if (tid < NB) {
    float S = 0.f;
    #pragma unroll
    for (int w = 0; w < 8; ++w) S += Spart[w * NB + tid];
    out[b0 + tid] = LN2 * (flog2(S) - (float)acc) - score[b0 + tid];
  }
}

__global__ __launch_bounds__(512, 1) void crf_scan(
    const float* __restrict__ yp, const unsigned short* __restrict__ Efrag,
    const unsigned char* __restrict__ masks, const float* __restrict__ score,
    float* __restrict__ out) {
  const int b0 = blockIdx.x * NB;
  const int tid = threadIdx.x;
  const int wv = tid >> 6, lane = tid & 63;
  const int c = lane & 15;       // batch column
  const int g = lane >> 4;       // k-group / row-group

  __shared__ unsigned short Wl[2][NB * WROW];  // ~16.9 KB
  __shared__ unsigned char mkl[T_ * NB];       // 8 KB
  __shared__ unsigned int Mpart[8 * NB];
  __shared__ float Spart[8 * NB];
  __shared__ int sflag[8];

  // E fragments -> registers: wave wv owns M-tiles {2wv, 2wv+1} (32 VGPR)
  short8 Ef[2][8];
  {
    const uint4* ep = (const uint4*)Efrag;
    #pragma unroll
    for (int m = 0; m < 2; ++m)
      #pragma unroll
      for (int kb = 0; kb < 8; ++kb)
        Ef[m][kb] = __builtin_bit_cast(short8, ep[((wv * 2 + m) * 8 + kb) * 64 + lane]);
  }

  // mask table -> LDS (mkl[t*16 + c]); also all-ones check
  uint4 md0;
  {
    uint4* dst = (uint4*)mkl;
    md0 = *(const uint4*)(masks + tid * 128 + b0);
    dst[tid] = md0;
  }

  const float* xb = yp + (size_t)(b0 + c) * T_ * K_;
  int tb[2];
  #pragma unroll
  for (int m = 0; m < 2; ++m) tb[m] = wv * 32 + m * 16 + g * 4;

  float4 xinit[2], X0q[2], X1q[2], X2q[2], X3q[2];
  #pragma unroll
  for (int m = 0; m < 2; ++m) xinit[m] = *(const float4*)(xb + tb[m]);
  #pragma unroll
  for (int m = 0; m < 2; ++m) X1q[m] = *(const float4*)(xb + 1 * K_ + tb[m]);
  #pragma unroll
  for (int m = 0; m < 2; ++m) X2q[m] = *(const float4*)(xb + 2 * K_ + tb[m]);
  #pragma unroll
  for (int m = 0; m < 2; ++m) X3q[m] = *(const float4*)(xb + 3 * K_ + tb[m]);
  #pragma unroll
  for (int m = 0; m < 2; ++m) X0q[m] = *(const float4*)(xb + 4 * K_ + tb[m]);

  // all-masks-one check (block-uniform)
  {
    uint32_t w = md0.x & md0.y & md0.z & md0.w;
    unsigned long long bl = __ballot(w == 0x01010101u);
    if (lane == 0) sflag[wv] = (bl == ~0ull) ? 1 : 0;
  }
  __syncthreads();
  bool allm = true;
  #pragma unroll
  for (int w = 0; w < 8; ++w) allm = allm && sflag[w];

  if (allm) {
    scan_run<false>(tid, c, g, wv, tb, b0, Ef, xb, xinit, X0q, X1q, X2q, X3q,
                    Wl, mkl, Mpart, Spart, score, out);
  } else {
    scan_run<true>(tid, c, g, wv, tb, b0, Ef, xb, xinit, X0q, X1q, X2q, X3q,
                   Wl, mkl, Mpart, Spart, score, out);
  }
}

extern "C" void kernel_launch(void* const* d_in, const int* in_sizes, int n_in,
                              void* d_out, int out_size, void* d_ws, size_t ws_size,
                              hipStream_t stream) {
  const float* yp = (const float*)d_in[0];
  const float* trans = (const float*)d_in[1];
  const int* ytrue = (const int*)d_in[2];
  float* out = (float*)d_out;

  unsigned short* Efrag = (unsigned short*)d_ws;                 // 128 KB
  unsigned char* masks = (unsigned char*)d_ws + 131072;          // 64 KB
  float* score = (float*)((char*)d_ws + 131072 + 65536);         // 512 B

  prep_E<<<dim3(256), dim3(256), 0, stream>>>(trans, Efrag);
  aux_mask<<<dim3(16384), dim3(256), 0, stream>>>(yp, masks);
  aux_score<<<dim3(128), dim3(64), 0, stream>>>(yp, trans, ytrue, masks, score);
  crf_scan<<<dim3(8), dim3(512), 0, stream>>>(yp, Efrag, masks, score, out);
}